// Round 11
// baseline (627.361 us; speedup 1.0000x reference)
//
#include <hip/hip_runtime.h>
#include <hip/hip_bf16.h>
#include <math.h>

#define T_LEN 512
#define B_SZ  256
#define I_SZ  300
#define H_SZ  64
#define G3    192   // 3H
#define TPG   3072  // 192*16 h16 per t-slice of one group
#define HPAD  80    // hs row stride (h16)

typedef float    f4v __attribute__((ext_vector_type(4)));
typedef _Float16 h4v __attribute__((ext_vector_type(4)));
typedef _Float16 h8v __attribute__((ext_vector_type(8)));

__device__ __forceinline__ float sigm_f(float x) {
    return __builtin_amdgcn_rcpf(1.f + __expf(-x));
}
__device__ __forceinline__ float tanh_f(float x) {
    float a = fabsf(x);
    float e = __expf(2.f * a);
    float t = 1.f - 2.f * __builtin_amdgcn_rcpf(1.f + e);
    return copysignf(t, x);
}

// ---------------------------------------------------------------------------
// Kernel 1: input projection, f16 MFMA (UNCHANGED from R10; ~230 µs, next
// target once its counters surface). xp2[d][G][t][g(192)][m(16)].
// ---------------------------------------------------------------------------
#define KC  64
#define NKC 5     // ceil(300/64)

__device__ __forceinline__ int stage_off(int j, int srow, int skq) {
    int g2 = (skq >> 1) & 3;
    return j * 1024 + (skq >> 3) * 512 + g2 * 128 + ((srow ^ (g2 << 1)) << 3) + (skq & 1) * 4;
}
__device__ __forceinline__ int frag_off(int tile, int kh, int lane) {
    int kgrp = lane >> 4, fr = lane & 15;
    return tile * 1024 + kh * 512 + kgrp * 128 + (((fr ^ (kgrp << 1))) << 3);
}

__global__ __launch_bounds__(256, 2) void proj_gemm(
    const float* __restrict__ x,
    const float* __restrict__ Wf, const float* __restrict__ bf,
    const float* __restrict__ Wb, const float* __restrict__ bb,
    _Float16* __restrict__ xp)
{
    __shared__ _Float16 Ap[8 * 1024];    // 16 KB
    __shared__ _Float16 Bp[12 * 1024];   // 24 KB

    const int tid = threadIdx.x;
    const int bid = blockIdx.x;          // 0..2047
    const int d   = bid >> 10;
    const int G   = (bid >> 6) & 15;     // batch group (16 b's)
    const int tc  = bid & 63;            // t-chunk (8 t's)

    const float* W    = d ? Wb : Wf;
    const float* bias = d ? bb : bf;

    const int srow = tid >> 4;           // 0..15  (= batch within group for A)
    const int skq  = tid & 15;           // k-quad (k' = skq*4)

    const int lane = tid & 63;
    const int w    = tid >> 6;           // 0..3
    const int wn   = (w >> 1) * 96;      // wave N offset

    f4v acc[4][6];
    #pragma unroll
    for (int mt = 0; mt < 4; ++mt)
        #pragma unroll
        for (int nt = 0; nt < 6; ++nt) acc[mt][nt] = (f4v)0.f;

    float4 av[8], bv[12];
    {
        const bool valid = (skq * 4) <= 296;
        #pragma unroll
        for (int j = 0; j < 8; ++j)
            av[j] = valid ? *(const float4*)(x + ((size_t)(G * 16 + srow) * T_LEN + tc * 8 + j) * I_SZ + skq * 4)
                          : float4{0.f, 0.f, 0.f, 0.f};
        #pragma unroll
        for (int j = 0; j < 12; ++j)
            bv[j] = valid ? *(const float4*)(W + (size_t)(j * 16 + srow) * I_SZ + skq * 4)
                          : float4{0.f, 0.f, 0.f, 0.f};
    }

    for (int kc = 0; kc < NKC; ++kc) {
        __syncthreads();

        #pragma unroll
        for (int j = 0; j < 8; ++j) {
            h4v c = { (_Float16)av[j].x, (_Float16)av[j].y,
                      (_Float16)av[j].z, (_Float16)av[j].w };
            *(h4v*)&Ap[stage_off(j, srow, skq)] = c;
        }
        #pragma unroll
        for (int j = 0; j < 12; ++j) {
            h4v c = { (_Float16)bv[j].x, (_Float16)bv[j].y,
                      (_Float16)bv[j].z, (_Float16)bv[j].w };
            *(h4v*)&Bp[stage_off(j, srow, skq)] = c;
        }
        __syncthreads();

        if (kc + 1 < NKC) {
            const int k0 = (kc + 1) * KC;
            const bool valid = (k0 + skq * 4) <= 296;
            #pragma unroll
            for (int j = 0; j < 8; ++j)
                av[j] = valid ? *(const float4*)(x + ((size_t)(G * 16 + srow) * T_LEN + tc * 8 + j) * I_SZ + k0 + skq * 4)
                              : float4{0.f, 0.f, 0.f, 0.f};
            #pragma unroll
            for (int j = 0; j < 12; ++j)
                bv[j] = valid ? *(const float4*)(W + (size_t)(j * 16 + srow) * I_SZ + k0 + skq * 4)
                              : float4{0.f, 0.f, 0.f, 0.f};
        }

        #pragma unroll
        for (int kh = 0; kh < 2; ++kh) {
            h8v bh_[6];
            #pragma unroll
            for (int nt = 0; nt < 6; ++nt)
                bh_[nt] = *(const h8v*)&Bp[frag_off((w >> 1) * 6 + nt, kh, lane)];
            #pragma unroll
            for (int mt = 0; mt < 4; ++mt) {
                h8v ah = *(const h8v*)&Ap[frag_off((w & 1) * 4 + mt, kh, lane)];
                #pragma unroll
                for (int nt = 0; nt < 6; ++nt)
                    acc[mt][nt] = __builtin_amdgcn_mfma_f32_16x16x32_f16(ah, bh_[nt], acc[mt][nt], 0, 0, 0);
            }
        }
    }

    const int col  = lane & 15;
    const int rowq = lane >> 4;
    float bias_v[6];
    #pragma unroll
    for (int nt = 0; nt < 6; ++nt) bias_v[nt] = bias[wn + nt * 16 + col];

    _Float16* obase = xp + (size_t)(d * 16 + G) * T_LEN * TPG;
    #pragma unroll
    for (int mt = 0; mt < 4; ++mt) {
        int t = tc * 8 + (w & 1) * 4 + mt;
        _Float16* ot = obase + (size_t)t * TPG;
        #pragma unroll
        for (int nt = 0; nt < 6; ++nt) {
            int g = wn + nt * 16 + col;
            h4v c = { (_Float16)(acc[mt][nt][0] + bias_v[nt]),
                      (_Float16)(acc[mt][nt][1] + bias_v[nt]),
                      (_Float16)(acc[mt][nt][2] + bias_v[nt]),
                      (_Float16)(acc[mt][nt][3] + bias_v[nt]) };
            *(h4v*)(ot + g * 16 + rowq * 4) = c;
        }
    }
}

// ---------------------------------------------------------------------------
// Kernel 2: GRU scan via MFMA, 16 blocks x 512 thr (8 waves).
// NEW vs R10: both directions' chains live in ONE block — waves 0-3 run d=0,
// waves 4-7 run d=1. Each SIMD hosts one wave from each chain, so the per-step
// latency chain (LDS RT + MFMA + transcendentals + barrier) of one chain is
// hidden by the other's issue (R10: 1 block/CU, nothing to hide -> 1100
// cyc/step). Wave w&3 owns u-slice [16(w&3), +16) across all 3 gates; gh
// never leaves the wave.
// ---------------------------------------------------------------------------
__global__ __launch_bounds__(512) void gru_scan(
    const _Float16* __restrict__ xp2,
    const float* __restrict__ Whf, const float* __restrict__ bhf,
    const float* __restrict__ Whb, const float* __restrict__ bhb,
    float* __restrict__ feat)
{
    const int tid  = threadIdx.x;
    const int lane = tid & 63;
    const int w    = tid >> 6;          // 0..7
    const int d    = w >> 2;            // direction = wave group
    const int ws   = w & 3;             // u-slice within direction
    const int G    = blockIdx.x;        // 0..15
    const int col  = lane & 15;
    const int quad = lane >> 4;
    const int u    = ws * 16 + col;     // hidden unit owned by this lane

    const float* Whh = d ? Whb : Whf;
    const float* bhh = d ? bhb : bhf;

    // B-frags for gates g=0(r),1(z),2(n): row n = g*64 + u
    h8v wb[3][2];
    f4v accb[3];
    int loff[3];
    #pragma unroll
    for (int g = 0; g < 3; ++g) {
        const int n = g * 64 + u;
        const float* wrow = Whh + (size_t)n * 64;
        #pragma unroll
        for (int c = 0; c < 2; ++c) {
            float4 w0 = *(const float4*)(wrow + c * 32 + quad * 8);
            float4 w1 = *(const float4*)(wrow + c * 32 + quad * 8 + 4);
            wb[g][c] = h8v{(_Float16)w0.x, (_Float16)w0.y, (_Float16)w0.z, (_Float16)w0.w,
                           (_Float16)w1.x, (_Float16)w1.y, (_Float16)w1.z, (_Float16)w1.w};
        }
        float bn = bhh[n];
        accb[g] = f4v{bn, bn, bn, bn};
        loff[g] = n * 16 + quad * 4;    // b64 slice: m = quad*4 .. +3
    }

    __shared__ _Float16 hs[2][2][16 * HPAD];   // [dir][buf][m*HPAD]
    for (int i = tid; i < 2 * 2 * 16 * HPAD; i += 512)
        ((_Float16*)hs)[i] = (_Float16)0.f;
    float hold[4] = {0.f, 0.f, 0.f, 0.f};

    const long tstep = d ? -(long)TPG : (long)TPG;
    const _Float16* base = xp2 + (size_t)(d * 16 + G) * T_LEN * TPG
                               + (size_t)(d ? T_LEN - 1 : 0) * TPG;

    h4v px[2][3];
    #pragma unroll
    for (int g = 0; g < 3; ++g) {
        px[0][g] = *(const h4v*)(base + loff[g]);
        px[1][g] = *(const h4v*)(base + tstep + loff[g]);
    }
    const _Float16* pnext = base + 2 * tstep;

    const int off_first = d ? 192 : 0;
    const int off_last  = d ? 64 : 128;

    __syncthreads();

    for (int s = 0; s < T_LEN; s += 2) {
        #pragma unroll
        for (int j = 0; j < 2; ++j) {
            const int sj = s + j;
            const _Float16* hrd = hs[d][j];        // read buffer (s+j parity)
            _Float16*       hwr = hs[d][j ^ 1];

            // A-frags: h[m=col][k] from LDS (contiguous 16B per lane)
            h8v a0 = *(const h8v*)&hrd[col * HPAD + quad * 8];
            h8v a1 = *(const h8v*)&hrd[col * HPAD + 32 + quad * 8];

            f4v gh[3];
            #pragma unroll
            for (int g = 0; g < 3; ++g) {
                f4v t0 = __builtin_amdgcn_mfma_f32_16x16x32_f16(a0, wb[g][0], accb[g], 0, 0, 0);
                gh[g]  = __builtin_amdgcn_mfma_f32_16x16x32_f16(a1, wb[g][1], t0, 0, 0, 0);
            }

            // capture current x before ring-slot refill (R8 lesson)
            h4v xc[3];
            #pragma unroll
            for (int g = 0; g < 3; ++g) xc[g] = px[j][g];
            if (sj + 2 < T_LEN) {
                #pragma unroll
                for (int g = 0; g < 3; ++g)
                    px[j][g] = *(const h4v*)(pnext + loff[g]);
                pnext += tstep;
            }

            // pointwise: 4 elements (m = quad*4+reg, u) — all operands local
            #pragma unroll
            for (int reg = 0; reg < 4; ++reg) {
                float r = sigm_f((float)xc[0][reg] + gh[0][reg]);
                float z = sigm_f((float)xc[1][reg] + gh[1][reg]);
                float n = tanh_f((float)xc[2][reg] + r * gh[2][reg]);
                float h = fmaf(z, hold[reg] - n, n);
                hold[reg] = h;
                hwr[(quad * 4 + reg) * HPAD + u] = (_Float16)h;
            }

            if (sj == 0) {
                #pragma unroll
                for (int reg = 0; reg < 4; ++reg)
                    feat[(G * 16 + quad * 4 + reg) * 256 + off_first + u] = hold[reg];
            }
            if (sj == T_LEN - 1) {
                #pragma unroll
                for (int reg = 0; reg < 4; ++reg)
                    feat[(G * 16 + quad * 4 + reg) * 256 + off_last + u] = hold[reg];
            }
            __syncthreads();   // h writes visible before next step's reads
        }
    }
}

// ---------------------------------------------------------------------------
// Kernel 3: MLP head. feat[b][256] -> 32 (LeakyReLU) -> 1
// ---------------------------------------------------------------------------
__global__ __launch_bounds__(64) void head_k(
    const float* __restrict__ feat,
    const float* __restrict__ W1, const float* __restrict__ b1,
    const float* __restrict__ W2, const float* __restrict__ b2,
    float* __restrict__ out)
{
    __shared__ float fs[256];
    const int b = blockIdx.x;
    const int tid = threadIdx.x;
    *(float4*)&fs[tid * 4] = *(const float4*)&feat[b * 256 + tid * 4];
    __syncthreads();
    float v = 0.f;
    if (tid < 32) {
        float a = b1[tid];
        const float4* Wv = (const float4*)(W1 + tid * 256);
        const float4* fv = (const float4*)fs;
        #pragma unroll 8
        for (int k = 0; k < 64; ++k) {
            float4 wv = Wv[k], f = fv[k];
            a += wv.x * f.x + wv.y * f.y + wv.z * f.z + wv.w * f.w;
        }
        a = a >= 0.f ? a : 0.01f * a;
        v = a * W2[tid];
    }
    #pragma unroll
    for (int off = 16; off > 0; off >>= 1) v += __shfl_down(v, off);
    if (tid == 0) out[b] = v + b2[0];
}

// ---------------------------------------------------------------------------
extern "C" void kernel_launch(void* const* d_in, const int* in_sizes, int n_in,
                              void* d_out, int out_size, void* d_ws, size_t ws_size,
                              hipStream_t stream)
{
    const float* x    = (const float*)d_in[0];
    const float* Wihf = (const float*)d_in[1];
    const float* Whhf = (const float*)d_in[2];
    const float* bihf = (const float*)d_in[3];
    const float* bhhf = (const float*)d_in[4];
    const float* Wihb = (const float*)d_in[5];
    const float* Whhb = (const float*)d_in[6];
    const float* bihb = (const float*)d_in[7];
    const float* bhhb = (const float*)d_in[8];
    const float* W1   = (const float*)d_in[9];
    const float* b1   = (const float*)d_in[10];
    const float* W2   = (const float*)d_in[11];
    const float* b2   = (const float*)d_in[12];
    float* out = (float*)d_out;

    _Float16* xp2  = (_Float16*)d_ws;                        // [d][G][t][g][16m], 100.7 MB
    float*    feat = (float*)((char*)d_ws + (size_t)2 * B_SZ * T_LEN * G3 * 2);

    proj_gemm<<<2048, 256, 0, stream>>>(x, Wihf, bihf, Wihb, bihb, xp2);
    gru_scan<<<16, 512, 0, stream>>>(xp2, Whhf, bhhf, Whhb, bhhb, feat);
    head_k<<<256, 64, 0, stream>>>(feat, W1, b1, W2, b2, out);
}